// Round 11
// baseline (250.810 us; speedup 1.0000x reference)
//
#include <hip/hip_runtime.h>
#include <hip/hip_fp16.h>

#define NB 8
#define LQ 2048
#define LKK 2048
#define DD 512

typedef _Float16 h16;
typedef __attribute__((ext_vector_type(4))) _Float16 h16x4;
typedef __attribute__((ext_vector_type(8))) _Float16 h16x8;
typedef __attribute__((ext_vector_type(4))) float f32x4;

// Static device scratch.
__device__ __attribute__((aligned(256))) h16 g_Vt[(size_t)NB * DD * LKK];   // [b][d][k]
__device__ __attribute__((aligned(256))) h16 g_P[(size_t)NB * LQ * LKK];    // exp(S) masked, f16
__device__ float g_part[(size_t)NB * LQ * 32];                              // 32 n-chunk partial sums per row

__constant__ float SCALE = 0.044194173824159216f; // 1/sqrt(512)

#define GLOAD_LDS16(gp, lp)                                                    \
  __builtin_amdgcn_global_load_lds(                                           \
      (const __attribute__((address_space(1))) void*)(gp),                     \
      (__attribute__((address_space(3))) void*)(lp), 16, 0, 0)

#define WAITV(N) asm volatile("s_waitcnt vmcnt(" #N ")" ::: "memory")

// ---------------- K0: convert + transpose V to [b][d][k] f16 ----------------
// nt LOADS (read-once fp32); regular stores (R8/R9: nt stores = write blowup).
__global__ void cvt_v(const float* __restrict__ v) {
  __shared__ h16 tile[64][66];
  const int j = blockIdx.x;                 // [0, 2048)
  const int b = j >> 8;
  const int k0 = (j & 31) * 64;
  const int d0 = ((j >> 5) & 7) * 64;
  const int t = threadIdx.x;
  const int c4 = (t & 15) * 4;
  const int r0 = t >> 4;
  const float* src = v + ((size_t)b * LKK + k0) * DD + d0;
#pragma unroll
  for (int p = 0; p < 4; p++) {
    const int row = r0 + p * 16;
    f32x4 val = __builtin_nontemporal_load((const f32x4*)(src + (size_t)row * DD + c4));
    tile[row][c4 + 0] = (h16)val[0];
    tile[row][c4 + 1] = (h16)val[1];
    tile[row][c4 + 2] = (h16)val[2];
    tile[row][c4 + 3] = (h16)val[3];
  }
  __syncthreads();
  h16* dst = g_Vt + ((size_t)b * DD + d0) * LKK + k0;
#pragma unroll
  for (int p = 0; p < 4; p++) {
    const int drow = r0 + p * 16;
    h16x4 h;
#pragma unroll
    for (int jj = 0; jj < 4; jj++) h[jj] = tile[c4 + jj][drow];
    *(h16x4*)(dst + (size_t)drow * LKK + c4) = h;
  }
}

// ---------------- K1: P = exp(mask(Q K^T / sqrt(d))) + partial row sums ------
// FUSED fp32->f16 staging: reg-staged (global f32x4 -> v_cvt -> swizzled
// ds_write), double-buffered, ONE barrier per k-step. Loads for tile k+1 fly
// under tile k's MFMA (T14). Regular loads: Q/K panels re-read 16x -> want L3.
__global__ __launch_bounds__(256) void qk_exp(const float* __restrict__ qf,
                                              const float* __restrict__ kf,
                                              const int* __restrict__ mask) {
  const int flat = blockIdx.z * (16 * 16) + blockIdx.y * 16 + blockIdx.x;
  const int fs = (flat & 7) * 256 + (flat >> 3);  // bijective XCD swizzle
  const int b = fs >> 8;
  const int m0 = ((fs >> 4) & 15) * 128, n0 = (fs & 15) * 128;

  const int tid = threadIdx.x, wave = tid >> 6, lane = tid & 63;
  const int wm = wave >> 1, wn = wave & 1;
  __shared__ __attribute__((aligned(16))) h16 Asw[2][128 * 64];  // 32 KB
  __shared__ __attribute__((aligned(16))) h16 Bsw[2][128 * 64];  // 32 KB
  const float* Agf = qf + ((size_t)b * LQ + m0) * DD;
  const float* Bgf = kf + ((size_t)b * LKK + n0) * DD;

  // staging ownership: thread -> (row, col-half). 2 threads per 128-elem row.
  const int srow = tid >> 1;   // 0..127
  const int sh = tid & 1;      // which 32-fp32 half of the 64-col tile

  f32x4 pa[8], pb[8];  // pending loads (compile-time indexed -> registers)
#define QK_LOAD(kk)                                                            \
  do {                                                                         \
    const float* ap = Agf + (size_t)srow * DD + (kk) * 64 + sh * 32;           \
    const float* bp = Bgf + (size_t)srow * DD + (kk) * 64 + sh * 32;           \
    _Pragma("unroll") for (int jj = 0; jj < 8; jj++) {                         \
      pa[jj] = *(const f32x4*)(ap + jj * 4);                                   \
      pb[jj] = *(const f32x4*)(bp + jj * 4);                                   \
    }                                                                          \
  } while (0)

  // write-side swizzle == read-side swizzle (chunk ^ (row & 7)) — rule #21.
#define QK_WRITE(buf)                                                          \
  do {                                                                         \
    _Pragma("unroll") for (int c = 0; c < 4; c++) {                            \
      const int chk = sh * 4 + c;                                              \
      const int off = srow * 64 + (chk ^ (srow & 7)) * 8;                      \
      h16x8 ha, hb;                                                            \
      _Pragma("unroll") for (int e = 0; e < 4; e++) {                          \
        ha[e] = (h16)pa[c * 2][e];     ha[e + 4] = (h16)pa[c * 2 + 1][e];      \
        hb[e] = (h16)pb[c * 2][e];     hb[e + 4] = (h16)pb[c * 2 + 1][e];      \
      }                                                                        \
      *(h16x8*)(&Asw[buf][off]) = ha;                                          \
      *(h16x8*)(&Bsw[buf][off]) = hb;                                          \
    }                                                                          \
  } while (0)

  f32x4 acc[4][4] = {};

  QK_LOAD(0);
  QK_WRITE(0);      // compiler inserts the vmcnt waits on pa/pb deps
  __syncthreads();  // buf0 ready

  for (int k = 0; k < 8; k++) {
    const int cur = k & 1;
    if (k < 7) QK_LOAD(k + 1);  // in flight across this tile's MFMA
    const h16* Ac = &Asw[cur][0];
    const h16* Bc = &Bsw[cur][0];
#pragma unroll
    for (int ks = 0; ks < 2; ks++) {
      h16x8 af[4], bf[4];
#pragma unroll
      for (int mf = 0; mf < 4; mf++) {
        const int rr = wm * 64 + mf * 16 + (lane & 15);
        const int chk = (ks * 4 + (lane >> 4)) ^ (rr & 7);
        af[mf] = *(const h16x8*)(Ac + rr * 64 + chk * 8);
      }
#pragma unroll
      for (int nf = 0; nf < 4; nf++) {
        const int rr = wn * 64 + nf * 16 + (lane & 15);
        const int chk = (ks * 4 + (lane >> 4)) ^ (rr & 7);
        bf[nf] = *(const h16x8*)(Bc + rr * 64 + chk * 8);
      }
#pragma unroll
      for (int mf = 0; mf < 4; mf++)
#pragma unroll
        for (int nf = 0; nf < 4; nf++)
          acc[mf][nf] = __builtin_amdgcn_mfma_f32_16x16x32_f16(af[mf], bf[nf], acc[mf][nf], 0, 0, 0);
    }
    if (k < 7) QK_WRITE(cur ^ 1);  // cvt + write next buf (reads of it done last iter)
    __syncthreads();               // writes visible + this buf's reads complete
  }

  const int cl = lane & 15, rg = lane >> 4;
  int mv[4];
#pragma unroll
  for (int nf = 0; nf < 4; nf++)
    mv[nf] = mask[b * LKK + n0 + wn * 64 + nf * 16 + cl];
  float rs[4][4] = {};
#pragma unroll
  for (int mf = 0; mf < 4; mf++) {
#pragma unroll
    for (int nf = 0; nf < 4; nf++) {
      const int colg = n0 + wn * 64 + nf * 16 + cl;
#pragma unroll
      for (int r = 0; r < 4; r++) {
        const int rowg = m0 + wm * 64 + mf * 16 + rg * 4 + r;
        const float p = mv[nf] ? 0.f : __expf(acc[mf][nf][r] * SCALE);
        g_P[((size_t)(b * LQ + rowg)) * LKK + colg] = (h16)p;
        rs[mf][r] += p;
      }
    }
  }
#pragma unroll
  for (int mf = 0; mf < 4; mf++)
#pragma unroll
    for (int r = 0; r < 4; r++) {
      float s = rs[mf][r];
      s += __shfl_xor(s, 1);
      s += __shfl_xor(s, 2);
      s += __shfl_xor(s, 4);
      s += __shfl_xor(s, 8);
      rs[mf][r] = s;
    }
  if (cl == 0) {
    const int pidx = (n0 >> 6) + wn;
#pragma unroll
    for (int mf = 0; mf < 4; mf++)
#pragma unroll
      for (int r = 0; r < 4; r++) {
        const int rowg = m0 + wm * 64 + mf * 16 + rg * 4 + r;
        g_part[(size_t)(b * LQ + rowg) * 32 + pidx] = rs[mf][r];
      }
  }
#undef QK_LOAD
#undef QK_WRITE
}

// ---------------- K2: O = (P V) * inv  AND  W = P * inv (dedup'd) ------------
// BM=128, BN=128. Counted-vmcnt pipeline (R6 structure). Regular stores.
__global__ __launch_bounds__(256) void pv_w(float* __restrict__ outv,
                                            float* __restrict__ wout) {
  const int flat = blockIdx.z * (4 * 16) + blockIdx.y * 4 + blockIdx.x;
  const int fs = (flat & 7) * 64 + (flat >> 3);   // bijective XCD swizzle
  const int b = fs >> 6;
  const int m0 = ((fs >> 2) & 15) * 128;
  const int bx = fs & 3;
  const int n0 = bx * 128;

  const int tid = threadIdx.x, wave = tid >> 6, lane = tid & 63;
  const int wm = wave >> 1, wn = wave & 1;
  __shared__ __attribute__((aligned(16))) h16 Asw[3][128 * 64];  // 48 KB
  __shared__ __attribute__((aligned(16))) h16 Bsw[2][128 * 64];  // 32 KB
  const h16* Ag = g_P + ((size_t)b * LQ + m0) * LKK;
  const h16* Bg = g_Vt + ((size_t)b * DD + n0) * LKK;
  const int rowA = lane >> 3;
  const int koff = ((lane & 7) ^ rowA) * 8;
  const int cl = lane & 15, rg = lane >> 4;

  float* inv_scr = (float*)&Asw[0][0];
  if (tid < 128) {
    const float* pp = g_part + (size_t)(b * LQ + m0 + tid) * 32;
    float s = 0.f;
#pragma unroll
    for (int i = 0; i < 8; i++) {
      f32x4 p4 = ((const f32x4*)pp)[i];
      s += p4[0] + p4[1] + p4[2] + p4[3];
    }
    inv_scr[tid] = (s > 0.f) ? 1.f / s : 0.f;
  }
  __syncthreads();
  float inv_m[4];    // rows wm*64 + mf*16 + cl   (W store rows)
  float inv_o[4][4]; // rows wm*64 + mf*16 + rg*4 + r (O epilogue rows)
#pragma unroll
  for (int mf = 0; mf < 4; mf++) {
    inv_m[mf] = inv_scr[wm * 64 + mf * 16 + cl];
#pragma unroll
    for (int r = 0; r < 4; r++)
      inv_o[mf][r] = inv_scr[wm * 64 + mf * 16 + rg * 4 + r];
  }
  __syncthreads();  // all inv reads done before Asw[0] is overwritten

#define PV_STAGE_A(abase, kk)                                                  \
  do {                                                                         \
    _Pragma("unroll") for (int i = 0; i < 4; i++) {                            \
      const int rr = (wave * 4 + i) * 8 + rowA;                                \
      GLOAD_LDS16(Ag + (size_t)rr * LKK + (kk) * 64 + koff,                    \
                  (abase) + (wave * 4 + i) * 512);                             \
    }                                                                          \
  } while (0)
#define PV_STAGE_B(bbase, kk)                                                  \
  do {                                                                         \
    _Pragma("unroll") for (int i = 0; i < 4; i++) {                            \
      const int rr = (wave * 4 + i) * 8 + rowA;                                \
      GLOAD_LDS16(Bg + (size_t)rr * LKK + (kk) * 64 + koff,                    \
                  (bbase) + (wave * 4 + i) * 512);                             \
    }                                                                          \
  } while (0)

  f32x4 acc[4][4] = {};
  h16x8 pend_af[4];
  int pend_col = -1;

  PV_STAGE_B(&Bsw[0][0], 0);
  PV_STAGE_A(&Asw[0][0], 0);
  PV_STAGE_A(&Asw[1][0], 1);

  int acur = 0;  // A buffer index of tile k (k % 3)
  for (int k = 0; k < 32; k++) {
    if (k < 31) PV_STAGE_B(&Bsw[(k + 1) & 1][0], k + 1);
    if (k < 30) {
      const int anext = (acur + 2 >= 3) ? acur - 1 : acur + 2;  // (k+2)%3
      PV_STAGE_A(&Asw[0][0] + anext * (128 * 64), k + 2);
    }
    if (k < 30) WAITV(12);
    else if (k == 30) WAITV(8);
    else WAITV(0);
    __builtin_amdgcn_s_barrier();  // tile k fully in LDS across all waves

    // flush deferred W stores from previous iteration (retire under MFMA)
    if (pend_col >= 0) {
#pragma unroll
      for (int mf = 0; mf < 4; mf++) {
        const int rowg = m0 + wm * 64 + mf * 16 + cl;
        float* wp = wout + ((size_t)b * LQ + rowg) * LKK + pend_col;
        f32x4 w0, w1;
        w0[0] = (float)pend_af[mf][0] * inv_m[mf];
        w0[1] = (float)pend_af[mf][1] * inv_m[mf];
        w0[2] = (float)pend_af[mf][2] * inv_m[mf];
        w0[3] = (float)pend_af[mf][3] * inv_m[mf];
        w1[0] = (float)pend_af[mf][4] * inv_m[mf];
        w1[1] = (float)pend_af[mf][5] * inv_m[mf];
        w1[2] = (float)pend_af[mf][6] * inv_m[mf];
        w1[3] = (float)pend_af[mf][7] * inv_m[mf];
        ((f32x4*)wp)[0] = w0;
        ((f32x4*)wp)[1] = w1;
      }
      pend_col = -1;
    }

    const h16* Ac = &Asw[0][0] + acur * (128 * 64);
    const h16* Bc = &Bsw[k & 1][0];
    const bool writeW = ((k >> 3) == bx);  // block owns W cols [k*64, k*64+64)
#pragma unroll
    for (int ks = 0; ks < 2; ks++) {
      h16x8 af[4], bf[4];
#pragma unroll
      for (int mf = 0; mf < 4; mf++) {
        const int rr = wm * 64 + mf * 16 + cl;
        const int chk = (ks * 4 + rg) ^ (rr & 7);
        af[mf] = *(const h16x8*)(Ac + rr * 64 + chk * 8);
      }
#pragma unroll
      for (int nf = 0; nf < 4; nf++) {
        const int rr = wn * 64 + nf * 16 + cl;
        const int chk = (ks * 4 + rg) ^ (rr & 7);
        bf[nf] = *(const h16x8*)(Bc + rr * 64 + chk * 8);
      }
#pragma unroll
      for (int mf = 0; mf < 4; mf++)
#pragma unroll
        for (int nf = 0; nf < 4; nf++)
          acc[mf][nf] = __builtin_amdgcn_mfma_f32_16x16x32_f16(af[mf], bf[nf], acc[mf][nf], 0, 0, 0);
      if (writeW && wn == ks) {
#pragma unroll
        for (int mf = 0; mf < 4; mf++) pend_af[mf] = af[mf];
        pend_col = k * 64 + (ks * 4 + rg) * 8;
      }
    }
    __builtin_amdgcn_s_barrier();  // all waves done reading tile k's buffers
    acur = (acur + 1 >= 3) ? 0 : acur + 1;
  }

  // flush last pending W (bx==3 owns k=31)
  if (pend_col >= 0) {
#pragma unroll
    for (int mf = 0; mf < 4; mf++) {
      const int rowg = m0 + wm * 64 + mf * 16 + cl;
      float* wp = wout + ((size_t)b * LQ + rowg) * LKK + pend_col;
      f32x4 w0, w1;
      w0[0] = (float)pend_af[mf][0] * inv_m[mf];
      w0[1] = (float)pend_af[mf][1] * inv_m[mf];
      w0[2] = (float)pend_af[mf][2] * inv_m[mf];
      w0[3] = (float)pend_af[mf][3] * inv_m[mf];
      w1[0] = (float)pend_af[mf][4] * inv_m[mf];
      w1[1] = (float)pend_af[mf][5] * inv_m[mf];
      w1[2] = (float)pend_af[mf][6] * inv_m[mf];
      w1[3] = (float)pend_af[mf][7] * inv_m[mf];
      ((f32x4*)wp)[0] = w0;
      ((f32x4*)wp)[1] = w1;
    }
  }

  // O epilogue
#pragma unroll
  for (int mf = 0; mf < 4; mf++) {
#pragma unroll
    for (int r = 0; r < 4; r++) {
      const int rowg = m0 + wm * 64 + mf * 16 + rg * 4 + r;
      const float inv = inv_o[mf][r];
#pragma unroll
      for (int nf = 0; nf < 4; nf++) {
        const int colg = n0 + wn * 64 + nf * 16 + cl;
        outv[((size_t)b * LQ + rowg) * DD + colg] = acc[mf][nf][r] * inv;
      }
    }
  }
#undef PV_STAGE_A
#undef PV_STAGE_B
}

extern "C" void kernel_launch(void* const* d_in, const int* in_sizes, int n_in,
                              void* d_out, int out_size, void* d_ws, size_t ws_size,
                              hipStream_t stream) {
  const float* q = (const float*)d_in[0];
  const float* k = (const float*)d_in[1];
  const float* v = (const float*)d_in[2];
  const int* mask = (const int*)d_in[3];
  float* o_val = (float*)d_out;                       // [8,2048,512]
  float* o_w = (float*)d_out + (size_t)NB * LQ * DD;  // [8,2048,2048]

  cvt_v<<<dim3(2048), dim3(256), 0, stream>>>(v);
  qk_exp<<<dim3(16, 16, NB), dim3(256), 0, stream>>>(q, k, mask);
  pv_w<<<dim3(4, 16, NB), dim3(256), 0, stream>>>(o_val, o_w);
}

// Round 12
// 146.861 us; speedup vs baseline: 1.7078x; 1.7078x over previous
//
#include <hip/hip_runtime.h>
#include <hip/hip_fp16.h>

#define NB 8
#define LQ 2048
#define LKK 2048
#define DD 512

typedef _Float16 h16;
typedef __attribute__((ext_vector_type(4))) _Float16 h16x4;
typedef __attribute__((ext_vector_type(8))) _Float16 h16x8;
typedef __attribute__((ext_vector_type(4))) float f32x4;

// Static device scratch.
__device__ __attribute__((aligned(256))) h16 g_Q[(size_t)NB * LQ * DD];
__device__ __attribute__((aligned(256))) h16 g_K[(size_t)NB * LKK * DD];
__device__ __attribute__((aligned(256))) h16 g_Vt[(size_t)NB * DD * LKK];   // [b][d][k]
__device__ __attribute__((aligned(256))) h16 g_P[(size_t)NB * LQ * LKK];    // exp(S) masked, f16
__device__ float g_part[(size_t)NB * LQ * 32];                              // 32 n-chunk partial sums per row

__constant__ float SCALE = 0.044194173824159216f; // 1/sqrt(512)

#define GLOAD_LDS16(gp, lp)                                                    \
  __builtin_amdgcn_global_load_lds(                                           \
      (const __attribute__((address_space(1))) void*)(gp),                     \
      (__attribute__((address_space(3))) void*)(lp), 16, 0, 0)

#define WAITV(N) asm volatile("s_waitcnt vmcnt(" #N ")" ::: "memory")

// ---------------- K0: convert Q,K (flat) to f16 ----------------
// nt LOADS (read-once fp32); regular stores (R8/R9: nt stores = write blowup).
__global__ void cvt_qk(const float* __restrict__ q, const float* __restrict__ k) {
  const int i = blockIdx.x * 256 + threadIdx.x;
  f32x4 vq = __builtin_nontemporal_load(((const f32x4*)q) + i);
  f32x4 vk = __builtin_nontemporal_load(((const f32x4*)k) + i);
  h16x4 hq, hk;
  hq[0] = (h16)vq[0]; hq[1] = (h16)vq[1]; hq[2] = (h16)vq[2]; hq[3] = (h16)vq[3];
  hk[0] = (h16)vk[0]; hk[1] = (h16)vk[1]; hk[2] = (h16)vk[2]; hk[3] = (h16)vk[3];
  ((h16x4*)g_Q)[i] = hq;
  ((h16x4*)g_K)[i] = hk;
}

// ---------------- K1: qk tiles (blocks <2048)  +  V-transpose (blocks >=2048)
// V blocks touch only v/g_Vt which qk blocks never access -> race-free fusion;
// V's HBM traffic fills qk's idle memory pipe (qk is latency-bound, ~20% occ).
__global__ __launch_bounds__(256) void qk_exp_v(const float* __restrict__ v,
                                                const int* __restrict__ mask) {
  const int tid = threadIdx.x;
  if (blockIdx.x >= 2048) {
    // ---- V convert+transpose tile (cvt_v of R10, nt loads) ----
    __shared__ h16 tile[64][66];
    const int j = blockIdx.x - 2048;          // [0, 2048)
    const int b = j >> 8;
    const int k0 = (j & 31) * 64;
    const int d0 = ((j >> 5) & 7) * 64;
    const int c4 = (tid & 15) * 4;
    const int r0 = tid >> 4;
    const float* src = v + ((size_t)b * LKK + k0) * DD + d0;
#pragma unroll
    for (int p = 0; p < 4; p++) {
      const int row = r0 + p * 16;
      f32x4 val = __builtin_nontemporal_load((const f32x4*)(src + (size_t)row * DD + c4));
      tile[row][c4 + 0] = (h16)val[0];
      tile[row][c4 + 1] = (h16)val[1];
      tile[row][c4 + 2] = (h16)val[2];
      tile[row][c4 + 3] = (h16)val[3];
    }
    __syncthreads();
    h16* dst = g_Vt + ((size_t)b * DD + d0) * LKK + k0;
#pragma unroll
    for (int p = 0; p < 4; p++) {
      const int drow = r0 + p * 16;
      h16x4 h;
#pragma unroll
      for (int jj = 0; jj < 4; jj++) h[jj] = tile[c4 + jj][drow];
      *(h16x4*)(dst + (size_t)drow * LKK + c4) = h;
    }
    return;
  }

  // ---- qk tile (R10 structure, unchanged) ----
  const int flat = blockIdx.x;
  const int fs = (flat & 7) * 256 + (flat >> 3);  // bijective XCD swizzle
  const int b = fs >> 8;
  const int m0 = ((fs >> 4) & 15) * 128, n0 = (fs & 15) * 128;

  const int wave = tid >> 6, lane = tid & 63;
  const int wm = wave >> 1, wn = wave & 1;
  __shared__ __attribute__((aligned(16))) h16 Asw[128 * 64];
  __shared__ __attribute__((aligned(16))) h16 Bsw[128 * 64];
  const h16* Ag = g_Q + ((size_t)b * LQ + m0) * DD;
  const h16* Bg = g_K + ((size_t)b * LKK + n0) * DD;
  const int rowA = lane >> 3;
  const int koff = ((lane & 7) ^ rowA) * 8;

  f32x4 acc[4][4] = {};

  for (int k0 = 0; k0 < DD; k0 += 64) {
#pragma unroll
    for (int i = 0; i < 4; i++) {
      const int rr = (wave * 4 + i) * 8 + rowA;
      GLOAD_LDS16(Ag + (size_t)rr * DD + k0 + koff, Asw + (wave * 4 + i) * 512);
      GLOAD_LDS16(Bg + (size_t)rr * DD + k0 + koff, Bsw + (wave * 4 + i) * 512);
    }
    __syncthreads();
#pragma unroll
    for (int ks = 0; ks < 2; ks++) {
      h16x8 af[4], bf[4];
#pragma unroll
      for (int mf = 0; mf < 4; mf++) {
        const int rr = wm * 64 + mf * 16 + (lane & 15);
        const int chk = (ks * 4 + (lane >> 4)) ^ (rr & 7);
        af[mf] = *(const h16x8*)(Asw + rr * 64 + chk * 8);
      }
#pragma unroll
      for (int nf = 0; nf < 4; nf++) {
        const int rr = wn * 64 + nf * 16 + (lane & 15);
        const int chk = (ks * 4 + (lane >> 4)) ^ (rr & 7);
        bf[nf] = *(const h16x8*)(Bsw + rr * 64 + chk * 8);
      }
#pragma unroll
      for (int mf = 0; mf < 4; mf++)
#pragma unroll
        for (int nf = 0; nf < 4; nf++)
          acc[mf][nf] = __builtin_amdgcn_mfma_f32_16x16x32_f16(af[mf], bf[nf], acc[mf][nf], 0, 0, 0);
    }
    __syncthreads();
  }

  const int cl = lane & 15, rg = lane >> 4;
  int mv[4];
#pragma unroll
  for (int nf = 0; nf < 4; nf++)
    mv[nf] = mask[b * LKK + n0 + wn * 64 + nf * 16 + cl];
  float rs[4][4] = {};
#pragma unroll
  for (int mf = 0; mf < 4; mf++) {
#pragma unroll
    for (int nf = 0; nf < 4; nf++) {
      const int colg = n0 + wn * 64 + nf * 16 + cl;
#pragma unroll
      for (int r = 0; r < 4; r++) {
        const int rowg = m0 + wm * 64 + mf * 16 + rg * 4 + r;
        const float p = mv[nf] ? 0.f : __expf(acc[mf][nf][r] * SCALE);
        g_P[((size_t)(b * LQ + rowg)) * LKK + colg] = (h16)p;
        rs[mf][r] += p;
      }
    }
  }
#pragma unroll
  for (int mf = 0; mf < 4; mf++)
#pragma unroll
    for (int r = 0; r < 4; r++) {
      float s = rs[mf][r];
      s += __shfl_xor(s, 1);
      s += __shfl_xor(s, 2);
      s += __shfl_xor(s, 4);
      s += __shfl_xor(s, 8);
      rs[mf][r] = s;
    }
  if (cl == 0) {
    const int pidx = (n0 >> 6) + wn;
#pragma unroll
    for (int mf = 0; mf < 4; mf++)
#pragma unroll
      for (int r = 0; r < 4; r++) {
        const int rowg = m0 + wm * 64 + mf * 16 + rg * 4 + r;
        g_part[(size_t)(b * LQ + rowg) * 32 + pidx] = rs[mf][r];
      }
  }
}

// ---------------- K2: O = (P V) * inv  AND  W = P * inv (dedup'd) ------------
// BM=128, BN=128. Counted-vmcnt pipeline (R6 structure). Regular stores.
__global__ __launch_bounds__(256) void pv_w(float* __restrict__ outv,
                                            float* __restrict__ wout) {
  const int flat = blockIdx.z * (4 * 16) + blockIdx.y * 4 + blockIdx.x;
  const int fs = (flat & 7) * 64 + (flat >> 3);   // bijective XCD swizzle
  const int b = fs >> 6;
  const int m0 = ((fs >> 2) & 15) * 128;
  const int bx = fs & 3;
  const int n0 = bx * 128;

  const int tid = threadIdx.x, wave = tid >> 6, lane = tid & 63;
  const int wm = wave >> 1, wn = wave & 1;
  __shared__ __attribute__((aligned(16))) h16 Asw[3][128 * 64];  // 48 KB
  __shared__ __attribute__((aligned(16))) h16 Bsw[2][128 * 64];  // 32 KB
  const h16* Ag = g_P + ((size_t)b * LQ + m0) * LKK;
  const h16* Bg = g_Vt + ((size_t)b * DD + n0) * LKK;
  const int rowA = lane >> 3;
  const int koff = ((lane & 7) ^ rowA) * 8;
  const int cl = lane & 15, rg = lane >> 4;

  float* inv_scr = (float*)&Asw[0][0];
  if (tid < 128) {
    const float* pp = g_part + (size_t)(b * LQ + m0 + tid) * 32;
    float s = 0.f;
#pragma unroll
    for (int i = 0; i < 8; i++) {
      f32x4 p4 = ((const f32x4*)pp)[i];
      s += p4[0] + p4[1] + p4[2] + p4[3];
    }
    inv_scr[tid] = (s > 0.f) ? 1.f / s : 0.f;
  }
  __syncthreads();
  float inv_m[4];    // rows wm*64 + mf*16 + cl   (W store rows)
  float inv_o[4][4]; // rows wm*64 + mf*16 + rg*4 + r (O epilogue rows)
#pragma unroll
  for (int mf = 0; mf < 4; mf++) {
    inv_m[mf] = inv_scr[wm * 64 + mf * 16 + cl];
#pragma unroll
    for (int r = 0; r < 4; r++)
      inv_o[mf][r] = inv_scr[wm * 64 + mf * 16 + rg * 4 + r];
  }
  __syncthreads();  // all inv reads done before Asw[0] is overwritten

#define PV_STAGE_A(abase, kk)                                                  \
  do {                                                                         \
    _Pragma("unroll") for (int i = 0; i < 4; i++) {                            \
      const int rr = (wave * 4 + i) * 8 + rowA;                                \
      GLOAD_LDS16(Ag + (size_t)rr * LKK + (kk) * 64 + koff,                    \
                  (abase) + (wave * 4 + i) * 512);                             \
    }                                                                          \
  } while (0)
#define PV_STAGE_B(bbase, kk)                                                  \
  do {                                                                         \
    _Pragma("unroll") for (int i = 0; i < 4; i++) {                            \
      const int rr = (wave * 4 + i) * 8 + rowA;                                \
      GLOAD_LDS16(Bg + (size_t)rr * LKK + (kk) * 64 + koff,                    \
                  (bbase) + (wave * 4 + i) * 512);                             \
    }                                                                          \
  } while (0)

  f32x4 acc[4][4] = {};
  h16x8 pend_af[4];
  int pend_col = -1;

  PV_STAGE_B(&Bsw[0][0], 0);
  PV_STAGE_A(&Asw[0][0], 0);
  PV_STAGE_A(&Asw[1][0], 1);

  int acur = 0;  // A buffer index of tile k (k % 3)
  for (int k = 0; k < 32; k++) {
    if (k < 31) PV_STAGE_B(&Bsw[(k + 1) & 1][0], k + 1);
    if (k < 30) {
      const int anext = (acur + 2 >= 3) ? acur - 1 : acur + 2;  // (k+2)%3
      PV_STAGE_A(&Asw[0][0] + anext * (128 * 64), k + 2);
    }
    if (k < 30) WAITV(12);
    else if (k == 30) WAITV(8);
    else WAITV(0);
    __builtin_amdgcn_s_barrier();  // tile k fully in LDS across all waves

    // flush deferred W stores from previous iteration (retire under MFMA)
    if (pend_col >= 0) {
#pragma unroll
      for (int mf = 0; mf < 4; mf++) {
        const int rowg = m0 + wm * 64 + mf * 16 + cl;
        float* wp = wout + ((size_t)b * LQ + rowg) * LKK + pend_col;
        f32x4 w0, w1;
        w0[0] = (float)pend_af[mf][0] * inv_m[mf];
        w0[1] = (float)pend_af[mf][1] * inv_m[mf];
        w0[2] = (float)pend_af[mf][2] * inv_m[mf];
        w0[3] = (float)pend_af[mf][3] * inv_m[mf];
        w1[0] = (float)pend_af[mf][4] * inv_m[mf];
        w1[1] = (float)pend_af[mf][5] * inv_m[mf];
        w1[2] = (float)pend_af[mf][6] * inv_m[mf];
        w1[3] = (float)pend_af[mf][7] * inv_m[mf];
        ((f32x4*)wp)[0] = w0;
        ((f32x4*)wp)[1] = w1;
      }
      pend_col = -1;
    }

    const h16* Ac = &Asw[0][0] + acur * (128 * 64);
    const h16* Bc = &Bsw[k & 1][0];
    const bool writeW = ((k >> 3) == bx);  // block owns W cols [k*64, k*64+64)
#pragma unroll
    for (int ks = 0; ks < 2; ks++) {
      h16x8 af[4], bf[4];
#pragma unroll
      for (int mf = 0; mf < 4; mf++) {
        const int rr = wm * 64 + mf * 16 + cl;
        const int chk = (ks * 4 + rg) ^ (rr & 7);
        af[mf] = *(const h16x8*)(Ac + rr * 64 + chk * 8);
      }
#pragma unroll
      for (int nf = 0; nf < 4; nf++) {
        const int rr = wn * 64 + nf * 16 + cl;
        const int chk = (ks * 4 + rg) ^ (rr & 7);
        bf[nf] = *(const h16x8*)(Bc + rr * 64 + chk * 8);
      }
#pragma unroll
      for (int mf = 0; mf < 4; mf++)
#pragma unroll
        for (int nf = 0; nf < 4; nf++)
          acc[mf][nf] = __builtin_amdgcn_mfma_f32_16x16x32_f16(af[mf], bf[nf], acc[mf][nf], 0, 0, 0);
      if (writeW && wn == ks) {
#pragma unroll
        for (int mf = 0; mf < 4; mf++) pend_af[mf] = af[mf];
        pend_col = k * 64 + (ks * 4 + rg) * 8;
      }
    }
    __builtin_amdgcn_s_barrier();  // all waves done reading tile k's buffers
    acur = (acur + 1 >= 3) ? 0 : acur + 1;
  }

  // flush last pending W (bx==3 owns k=31)
  if (pend_col >= 0) {
#pragma unroll
    for (int mf = 0; mf < 4; mf++) {
      const int rowg = m0 + wm * 64 + mf * 16 + cl;
      float* wp = wout + ((size_t)b * LQ + rowg) * LKK + pend_col;
      f32x4 w0, w1;
      w0[0] = (float)pend_af[mf][0] * inv_m[mf];
      w0[1] = (float)pend_af[mf][1] * inv_m[mf];
      w0[2] = (float)pend_af[mf][2] * inv_m[mf];
      w0[3] = (float)pend_af[mf][3] * inv_m[mf];
      w1[0] = (float)pend_af[mf][4] * inv_m[mf];
      w1[1] = (float)pend_af[mf][5] * inv_m[mf];
      w1[2] = (float)pend_af[mf][6] * inv_m[mf];
      w1[3] = (float)pend_af[mf][7] * inv_m[mf];
      ((f32x4*)wp)[0] = w0;
      ((f32x4*)wp)[1] = w1;
    }
  }

  // O epilogue
#pragma unroll
  for (int mf = 0; mf < 4; mf++) {
#pragma unroll
    for (int r = 0; r < 4; r++) {
      const int rowg = m0 + wm * 64 + mf * 16 + rg * 4 + r;
      const float inv = inv_o[mf][r];
#pragma unroll
      for (int nf = 0; nf < 4; nf++) {
        const int colg = n0 + wn * 64 + nf * 16 + cl;
        outv[((size_t)b * LQ + rowg) * DD + colg] = acc[mf][nf][r] * inv;
      }
    }
  }
#undef PV_STAGE_A
#undef PV_STAGE_B
}

extern "C" void kernel_launch(void* const* d_in, const int* in_sizes, int n_in,
                              void* d_out, int out_size, void* d_ws, size_t ws_size,
                              hipStream_t stream) {
  const float* q = (const float*)d_in[0];
  const float* k = (const float*)d_in[1];
  const float* v = (const float*)d_in[2];
  const int* mask = (const int*)d_in[3];
  float* o_val = (float*)d_out;                       // [8,2048,512]
  float* o_w = (float*)d_out + (size_t)NB * LQ * DD;  // [8,2048,2048]

  cvt_qk<<<dim3(NB * LQ * DD / 4 / 256), dim3(256), 0, stream>>>(q, k);
  qk_exp_v<<<dim3(2048 + 2048), dim3(256), 0, stream>>>(v, mask);
  pv_w<<<dim3(4, 16, NB), dim3(256), 0, stream>>>(o_val, o_w);
}

// Round 13
// 143.457 us; speedup vs baseline: 1.7483x; 1.0237x over previous
//
#include <hip/hip_runtime.h>
#include <hip/hip_fp16.h>

#define NB 8
#define LQ 2048
#define LKK 2048
#define DD 512

typedef _Float16 h16;
typedef __attribute__((ext_vector_type(4))) _Float16 h16x4;
typedef __attribute__((ext_vector_type(8))) _Float16 h16x8;
typedef __attribute__((ext_vector_type(4))) float f32x4;

// Static device scratch.
__device__ __attribute__((aligned(256))) h16 g_Q[(size_t)NB * LQ * DD];
__device__ __attribute__((aligned(256))) h16 g_K[(size_t)NB * LKK * DD];
__device__ __attribute__((aligned(256))) h16 g_Vt[(size_t)NB * DD * LKK];   // [b][d][k]
__device__ __attribute__((aligned(256))) h16 g_P[(size_t)NB * LQ * LKK];    // exp(S) masked, f16
__device__ float g_part[(size_t)NB * LQ * 32];                              // 32 n-chunk partial sums per row

__constant__ float SCALE = 0.044194173824159216f; // 1/sqrt(512)

#define GLOAD_LDS16(gp, lp)                                                    \
  __builtin_amdgcn_global_load_lds(                                           \
      (const __attribute__((address_space(1))) void*)(gp),                     \
      (__attribute__((address_space(3))) void*)(lp), 16, 0, 0)

#define WAITV(N) asm volatile("s_waitcnt vmcnt(" #N ")" ::: "memory")

// ---------------- K0: convert Q,K (flat) to f16 ----------------
// nt LOADS (read-once fp32); regular stores (R8/R9: nt stores = write blowup).
__global__ void cvt_qk(const float* __restrict__ q, const float* __restrict__ k) {
  const int i = blockIdx.x * 256 + threadIdx.x;
  f32x4 vq = __builtin_nontemporal_load(((const f32x4*)q) + i);
  f32x4 vk = __builtin_nontemporal_load(((const f32x4*)k) + i);
  h16x4 hq, hk;
  hq[0] = (h16)vq[0]; hq[1] = (h16)vq[1]; hq[2] = (h16)vq[2]; hq[3] = (h16)vq[3];
  hk[0] = (h16)vk[0]; hk[1] = (h16)vk[1]; hk[2] = (h16)vk[2]; hk[3] = (h16)vk[3];
  ((h16x4*)g_Q)[i] = hq;
  ((h16x4*)g_K)[i] = hk;
}

// ---------------- K1: qk tiles (blocks <2048)  +  V-transpose (blocks >=2048)
// qk loop: LDS dbuf, ONE barrier per k-step, next-tile stage issued before
// MFMA (drains under compute, R5 pattern) + T5 setprio around MFMA cluster.
__global__ __launch_bounds__(256) void qk_exp_v(const float* __restrict__ v,
                                                const int* __restrict__ mask) {
  const int tid = threadIdx.x;
  if (blockIdx.x >= 2048) {
    // ---- V convert+transpose tile (nt loads) ----
    __shared__ h16 tile[64][66];
    const int j = blockIdx.x - 2048;          // [0, 2048)
    const int b = j >> 8;
    const int k0 = (j & 31) * 64;
    const int d0 = ((j >> 5) & 7) * 64;
    const int c4 = (tid & 15) * 4;
    const int r0 = tid >> 4;
    const float* src = v + ((size_t)b * LKK + k0) * DD + d0;
#pragma unroll
    for (int p = 0; p < 4; p++) {
      const int row = r0 + p * 16;
      f32x4 val = __builtin_nontemporal_load((const f32x4*)(src + (size_t)row * DD + c4));
      tile[row][c4 + 0] = (h16)val[0];
      tile[row][c4 + 1] = (h16)val[1];
      tile[row][c4 + 2] = (h16)val[2];
      tile[row][c4 + 3] = (h16)val[3];
    }
    __syncthreads();
    h16* dst = g_Vt + ((size_t)b * DD + d0) * LKK + k0;
#pragma unroll
    for (int p = 0; p < 4; p++) {
      const int drow = r0 + p * 16;
      h16x4 h;
#pragma unroll
      for (int jj = 0; jj < 4; jj++) h[jj] = tile[c4 + jj][drow];
      *(h16x4*)(dst + (size_t)drow * LKK + c4) = h;
    }
    return;
  }

  // ---- qk tile ----
  const int flat = blockIdx.x;
  const int fs = (flat & 7) * 256 + (flat >> 3);  // bijective XCD swizzle
  const int b = fs >> 8;
  const int m0 = ((fs >> 4) & 15) * 128, n0 = (fs & 15) * 128;

  const int wave = tid >> 6, lane = tid & 63;
  const int wm = wave >> 1, wn = wave & 1;
  __shared__ __attribute__((aligned(16))) h16 Asw[2][128 * 64];  // 32 KB
  __shared__ __attribute__((aligned(16))) h16 Bsw[2][128 * 64];  // 32 KB
  const h16* Ag = g_Q + ((size_t)b * LQ + m0) * DD;
  const h16* Bg = g_K + ((size_t)b * LKK + n0) * DD;
  const int rowA = lane >> 3;
  const int koff = ((lane & 7) ^ rowA) * 8;

#define QK_STAGE(buf, kk)                                                      \
  do {                                                                         \
    _Pragma("unroll") for (int i = 0; i < 4; i++) {                            \
      const int rr = (wave * 4 + i) * 8 + rowA;                                \
      GLOAD_LDS16(Ag + (size_t)rr * DD + (kk) * 64 + koff,                     \
                  &Asw[buf][(wave * 4 + i) * 512]);                            \
      GLOAD_LDS16(Bg + (size_t)rr * DD + (kk) * 64 + koff,                     \
                  &Bsw[buf][(wave * 4 + i) * 512]);                            \
    }                                                                          \
  } while (0)

  f32x4 acc[4][4] = {};

  QK_STAGE(0, 0);
  __syncthreads();  // buf0 ready

  for (int kt = 0; kt < 8; kt++) {
    const int cur = kt & 1;
    if (kt < 7) QK_STAGE(cur ^ 1, kt + 1);  // in flight across this tile's MFMA
    const h16* Ac = &Asw[cur][0];
    const h16* Bc = &Bsw[cur][0];
    __builtin_amdgcn_s_setprio(1);
#pragma unroll
    for (int ks = 0; ks < 2; ks++) {
      h16x8 af[4], bf[4];
#pragma unroll
      for (int mf = 0; mf < 4; mf++) {
        const int rr = wm * 64 + mf * 16 + (lane & 15);
        const int chk = (ks * 4 + (lane >> 4)) ^ (rr & 7);
        af[mf] = *(const h16x8*)(Ac + rr * 64 + chk * 8);
      }
#pragma unroll
      for (int nf = 0; nf < 4; nf++) {
        const int rr = wn * 64 + nf * 16 + (lane & 15);
        const int chk = (ks * 4 + (lane >> 4)) ^ (rr & 7);
        bf[nf] = *(const h16x8*)(Bc + rr * 64 + chk * 8);
      }
#pragma unroll
      for (int mf = 0; mf < 4; mf++)
#pragma unroll
        for (int nf = 0; nf < 4; nf++)
          acc[mf][nf] = __builtin_amdgcn_mfma_f32_16x16x32_f16(af[mf], bf[nf], acc[mf][nf], 0, 0, 0);
    }
    __builtin_amdgcn_s_setprio(0);
    __syncthreads();  // next buf staged + this buf's reads complete
  }
#undef QK_STAGE

  const int cl = lane & 15, rg = lane >> 4;
  int mv[4];
#pragma unroll
  for (int nf = 0; nf < 4; nf++)
    mv[nf] = mask[b * LKK + n0 + wn * 64 + nf * 16 + cl];
  float rs[4][4] = {};
#pragma unroll
  for (int mf = 0; mf < 4; mf++) {
#pragma unroll
    for (int nf = 0; nf < 4; nf++) {
      const int colg = n0 + wn * 64 + nf * 16 + cl;
#pragma unroll
      for (int r = 0; r < 4; r++) {
        const int rowg = m0 + wm * 64 + mf * 16 + rg * 4 + r;
        const float p = mv[nf] ? 0.f : __expf(acc[mf][nf][r] * SCALE);
        g_P[((size_t)(b * LQ + rowg)) * LKK + colg] = (h16)p;
        rs[mf][r] += p;
      }
    }
  }
#pragma unroll
  for (int mf = 0; mf < 4; mf++)
#pragma unroll
    for (int r = 0; r < 4; r++) {
      float s = rs[mf][r];
      s += __shfl_xor(s, 1);
      s += __shfl_xor(s, 2);
      s += __shfl_xor(s, 4);
      s += __shfl_xor(s, 8);
      rs[mf][r] = s;
    }
  if (cl == 0) {
    const int pidx = (n0 >> 6) + wn;
#pragma unroll
    for (int mf = 0; mf < 4; mf++)
#pragma unroll
      for (int r = 0; r < 4; r++) {
        const int rowg = m0 + wm * 64 + mf * 16 + rg * 4 + r;
        g_part[(size_t)(b * LQ + rowg) * 32 + pidx] = rs[mf][r];
      }
  }
}

// ---------------- K2: O = (P V) * inv  AND  W = P * inv (dedup'd) ------------
// BM=128, BN=128. Counted-vmcnt pipeline (R6 structure) + T5 setprio.
__global__ __launch_bounds__(256) void pv_w(float* __restrict__ outv,
                                            float* __restrict__ wout) {
  const int flat = blockIdx.z * (4 * 16) + blockIdx.y * 4 + blockIdx.x;
  const int fs = (flat & 7) * 64 + (flat >> 3);   // bijective XCD swizzle
  const int b = fs >> 6;
  const int m0 = ((fs >> 2) & 15) * 128;
  const int bx = fs & 3;
  const int n0 = bx * 128;

  const int tid = threadIdx.x, wave = tid >> 6, lane = tid & 63;
  const int wm = wave >> 1, wn = wave & 1;
  __shared__ __attribute__((aligned(16))) h16 Asw[3][128 * 64];  // 48 KB
  __shared__ __attribute__((aligned(16))) h16 Bsw[2][128 * 64];  // 32 KB
  const h16* Ag = g_P + ((size_t)b * LQ + m0) * LKK;
  const h16* Bg = g_Vt + ((size_t)b * DD + n0) * LKK;
  const int rowA = lane >> 3;
  const int koff = ((lane & 7) ^ rowA) * 8;
  const int cl = lane & 15, rg = lane >> 4;

  float* inv_scr = (float*)&Asw[0][0];
  if (tid < 128) {
    const float* pp = g_part + (size_t)(b * LQ + m0 + tid) * 32;
    float s = 0.f;
#pragma unroll
    for (int i = 0; i < 8; i++) {
      f32x4 p4 = ((const f32x4*)pp)[i];
      s += p4[0] + p4[1] + p4[2] + p4[3];
    }
    inv_scr[tid] = (s > 0.f) ? 1.f / s : 0.f;
  }
  __syncthreads();
  float inv_m[4];    // rows wm*64 + mf*16 + cl   (W store rows)
  float inv_o[4][4]; // rows wm*64 + mf*16 + rg*4 + r (O epilogue rows)
#pragma unroll
  for (int mf = 0; mf < 4; mf++) {
    inv_m[mf] = inv_scr[wm * 64 + mf * 16 + cl];
#pragma unroll
    for (int r = 0; r < 4; r++)
      inv_o[mf][r] = inv_scr[wm * 64 + mf * 16 + rg * 4 + r];
  }
  __syncthreads();  // all inv reads done before Asw[0] is overwritten

#define PV_STAGE_A(abase, kk)                                                  \
  do {                                                                         \
    _Pragma("unroll") for (int i = 0; i < 4; i++) {                            \
      const int rr = (wave * 4 + i) * 8 + rowA;                                \
      GLOAD_LDS16(Ag + (size_t)rr * LKK + (kk) * 64 + koff,                    \
                  (abase) + (wave * 4 + i) * 512);                             \
    }                                                                          \
  } while (0)
#define PV_STAGE_B(bbase, kk)                                                  \
  do {                                                                         \
    _Pragma("unroll") for (int i = 0; i < 4; i++) {                            \
      const int rr = (wave * 4 + i) * 8 + rowA;                                \
      GLOAD_LDS16(Bg + (size_t)rr * LKK + (kk) * 64 + koff,                    \
                  (bbase) + (wave * 4 + i) * 512);                             \
    }                                                                          \
  } while (0)

  f32x4 acc[4][4] = {};
  h16x8 pend_af[4];
  int pend_col = -1;

  PV_STAGE_B(&Bsw[0][0], 0);
  PV_STAGE_A(&Asw[0][0], 0);
  PV_STAGE_A(&Asw[1][0], 1);

  int acur = 0;  // A buffer index of tile k (k % 3)
  for (int k = 0; k < 32; k++) {
    if (k < 31) PV_STAGE_B(&Bsw[(k + 1) & 1][0], k + 1);
    if (k < 30) {
      const int anext = (acur + 2 >= 3) ? acur - 1 : acur + 2;  // (k+2)%3
      PV_STAGE_A(&Asw[0][0] + anext * (128 * 64), k + 2);
    }
    if (k < 30) WAITV(12);
    else if (k == 30) WAITV(8);
    else WAITV(0);
    __builtin_amdgcn_s_barrier();  // tile k fully in LDS across all waves

    // flush deferred W stores from previous iteration (retire under MFMA)
    if (pend_col >= 0) {
#pragma unroll
      for (int mf = 0; mf < 4; mf++) {
        const int rowg = m0 + wm * 64 + mf * 16 + cl;
        float* wp = wout + ((size_t)b * LQ + rowg) * LKK + pend_col;
        f32x4 w0, w1;
        w0[0] = (float)pend_af[mf][0] * inv_m[mf];
        w0[1] = (float)pend_af[mf][1] * inv_m[mf];
        w0[2] = (float)pend_af[mf][2] * inv_m[mf];
        w0[3] = (float)pend_af[mf][3] * inv_m[mf];
        w1[0] = (float)pend_af[mf][4] * inv_m[mf];
        w1[1] = (float)pend_af[mf][5] * inv_m[mf];
        w1[2] = (float)pend_af[mf][6] * inv_m[mf];
        w1[3] = (float)pend_af[mf][7] * inv_m[mf];
        ((f32x4*)wp)[0] = w0;
        ((f32x4*)wp)[1] = w1;
      }
      pend_col = -1;
    }

    const h16* Ac = &Asw[0][0] + acur * (128 * 64);
    const h16* Bc = &Bsw[k & 1][0];
    const bool writeW = ((k >> 3) == bx);  // block owns W cols [k*64, k*64+64)
    __builtin_amdgcn_s_setprio(1);
#pragma unroll
    for (int ks = 0; ks < 2; ks++) {
      h16x8 af[4], bf[4];
#pragma unroll
      for (int mf = 0; mf < 4; mf++) {
        const int rr = wm * 64 + mf * 16 + cl;
        const int chk = (ks * 4 + rg) ^ (rr & 7);
        af[mf] = *(const h16x8*)(Ac + rr * 64 + chk * 8);
      }
#pragma unroll
      for (int nf = 0; nf < 4; nf++) {
        const int rr = wn * 64 + nf * 16 + cl;
        const int chk = (ks * 4 + rg) ^ (rr & 7);
        bf[nf] = *(const h16x8*)(Bc + rr * 64 + chk * 8);
      }
#pragma unroll
      for (int mf = 0; mf < 4; mf++)
#pragma unroll
        for (int nf = 0; nf < 4; nf++)
          acc[mf][nf] = __builtin_amdgcn_mfma_f32_16x16x32_f16(af[mf], bf[nf], acc[mf][nf], 0, 0, 0);
      if (writeW && wn == ks) {
#pragma unroll
        for (int mf = 0; mf < 4; mf++) pend_af[mf] = af[mf];
        pend_col = k * 64 + (ks * 4 + rg) * 8;
      }
    }
    __builtin_amdgcn_s_setprio(0);
    __builtin_amdgcn_s_barrier();  // all waves done reading tile k's buffers
    acur = (acur + 1 >= 3) ? 0 : acur + 1;
  }

  // flush last pending W (bx==3 owns k=31)
  if (pend_col >= 0) {
#pragma unroll
    for (int mf = 0; mf < 4; mf++) {
      const int rowg = m0 + wm * 64 + mf * 16 + cl;
      float* wp = wout + ((size_t)b * LQ + rowg) * LKK + pend_col;
      f32x4 w0, w1;
      w0[0] = (float)pend_af[mf][0] * inv_m[mf];
      w0[1] = (float)pend_af[mf][1] * inv_m[mf];
      w0[2] = (float)pend_af[mf][2] * inv_m[mf];
      w0[3] = (float)pend_af[mf][3] * inv_m[mf];
      w1[0] = (float)pend_af[mf][4] * inv_m[mf];
      w1[1] = (float)pend_af[mf][5] * inv_m[mf];
      w1[2] = (float)pend_af[mf][6] * inv_m[mf];
      w1[3] = (float)pend_af[mf][7] * inv_m[mf];
      ((f32x4*)wp)[0] = w0;
      ((f32x4*)wp)[1] = w1;
    }
  }

  // O epilogue
#pragma unroll
  for (int mf = 0; mf < 4; mf++) {
#pragma unroll
    for (int r = 0; r < 4; r++) {
      const int rowg = m0 + wm * 64 + mf * 16 + rg * 4 + r;
      const float inv = inv_o[mf][r];
#pragma unroll
      for (int nf = 0; nf < 4; nf++) {
        const int colg = n0 + wn * 64 + nf * 16 + cl;
        outv[((size_t)b * LQ + rowg) * DD + colg] = acc[mf][nf][r] * inv;
      }
    }
  }
#undef PV_STAGE_A
#undef PV_STAGE_B
}

extern "C" void kernel_launch(void* const* d_in, const int* in_sizes, int n_in,
                              void* d_out, int out_size, void* d_ws, size_t ws_size,
                              hipStream_t stream) {
  const float* q = (const float*)d_in[0];
  const float* k = (const float*)d_in[1];
  const float* v = (const float*)d_in[2];
  const int* mask = (const int*)d_in[3];
  float* o_val = (float*)d_out;                       // [8,2048,512]
  float* o_w = (float*)d_out + (size_t)NB * LQ * DD;  // [8,2048,2048]

  cvt_qk<<<dim3(NB * LQ * DD / 4 / 256), dim3(256), 0, stream>>>(q, k);
  qk_exp_v<<<dim3(2048 + 2048), dim3(256), 0, stream>>>(v, mask);
  pv_w<<<dim3(4, 16, NB), dim3(256), 0, stream>>>(o_val, o_w);
}